// Round 5
// baseline (2148.055 us; speedup 1.0000x reference)
//
#include <hip/hip_runtime.h>
#include <stdint.h>

#define T_TOK 16384
#define DIM 512
#define HID 2048
#define NE 16
#define TOPK 4
#define BM 128
#define BN 128
#define BK 64
#define PAIR_CAP 67584      // 65536 + 16*128 padding
#define MAX_TILES 528       // PAIR_CAP / BM
#define NB_CNT 64

// meta layout (ints): [0]=tiles_total, [1..17]=padded offsets po[0..16],
// [32..1055]=blockbase[64][16], [1056..2079]=hist[64][16],
// [2080]=work queue counter, [2112..2655]=g1done[544], [2656..3199]=g2done[544]
#define MQ_CTR 2080
#define MQ_G1  2112
#define MQ_G2  2656

typedef short s8v __attribute__((ext_vector_type(8)));
typedef float f4v __attribute__((ext_vector_type(4)));
typedef unsigned int u4v __attribute__((ext_vector_type(4)));

__device__ __forceinline__ unsigned short f2bf(float f) {
  unsigned int u = __builtin_bit_cast(unsigned int, f);
  u = (u + 0x7fffu + ((u >> 16) & 1u)) >> 16;
  return (unsigned short)u;
}
__device__ __forceinline__ float bf2f(unsigned short h) {
  return __builtin_bit_cast(float, (unsigned int)h << 16);
}

// async global->LDS, 16B per lane. LDS dest is wave-uniform base + lane*16.
__device__ __forceinline__ void gload16(const void* g, void* l) {
  __builtin_amdgcn_global_load_lds(
      (const __attribute__((address_space(1))) unsigned int*)(uintptr_t)g,
      (__attribute__((address_space(3))) unsigned int*)(uintptr_t)l,
      16, 0, 0);
}

// src [z][R][C] fp32 -> dst [z][C][R] bf16
__global__ __launch_bounds__(256) void k_transpose_cast(const float* __restrict__ src,
                                                        unsigned short* __restrict__ dst,
                                                        int R, int C) {
  __shared__ float tile[32][33];
  size_t zo = (size_t)blockIdx.z * R * C;
  src += zo; dst += zo;
  int c0 = blockIdx.x * 32, r0 = blockIdx.y * 32;
  int tx = threadIdx.x, ty = threadIdx.y;
#pragma unroll
  for (int i = 0; i < 4; ++i)
    tile[ty + 8 * i][tx] = src[(size_t)(r0 + ty + 8 * i) * C + c0 + tx];
  __syncthreads();
#pragma unroll
  for (int i = 0; i < 4; ++i)
    dst[(size_t)(c0 + ty + 8 * i) * R + r0 + tx] = f2bf(tile[tx][ty + 8 * i]);
}

// ---------------- routing (+ fused x->bf16 cast) ----------------
__global__ __launch_bounds__(256) void k_router(const float* __restrict__ x,
                                                const float* __restrict__ rw,
                                                const float* __restrict__ rb,
                                                int* __restrict__ topki,
                                                float* __restrict__ topkg,
                                                unsigned short* __restrict__ xb) {
  int wv = threadIdx.x >> 6, lane = threadIdx.x & 63;
  int t = blockIdx.x * 4 + wv;
  const float* xr = x + (size_t)t * DIM;
  unsigned short* xbr = xb + (size_t)t * DIM;
  double acc[NE];
#pragma unroll
  for (int e = 0; e < NE; ++e) acc[e] = 0.0;
  for (int it = 0; it < DIM / 64; ++it) {
    float xv = xr[it * 64 + lane];
    xbr[it * 64 + lane] = f2bf(xv);
    const float* r = rw + (size_t)(it * 64 + lane) * NE;
#pragma unroll
    for (int e = 0; e < NE; ++e) acc[e] += (double)xv * (double)r[e];
  }
#pragma unroll
  for (int off = 32; off >= 1; off >>= 1) {
#pragma unroll
    for (int e = 0; e < NE; ++e) acc[e] += __shfl_xor(acc[e], off, 64);
  }
  if (lane == 0) {
    float v[NE];
#pragma unroll
    for (int e = 0; e < NE; ++e) v[e] = (float)acc[e] + rb[e];
    int idx[TOPK]; float val[TOPK];
#pragma unroll
    for (int k = 0; k < TOPK; ++k) {
      float best = -1e30f; int bi = 0;
#pragma unroll
      for (int e = 0; e < NE; ++e)
        if (v[e] > best) { best = v[e]; bi = e; }
      idx[k] = bi; val[k] = best; v[bi] = -1e30f;
    }
    float m = val[0], s = 0.f, g[TOPK];
#pragma unroll
    for (int k = 0; k < TOPK; ++k) { g[k] = __expf(val[k] - m); s += g[k]; }
    float inv = 1.f / s;
#pragma unroll
    for (int k = 0; k < TOPK; ++k) {
      topki[t * TOPK + k] = idx[k];
      topkg[t * TOPK + k] = g[k] * inv;
    }
  }
}

__global__ __launch_bounds__(256) void k_count(const int* __restrict__ topki,
                                               int* __restrict__ meta) {
  __shared__ int lcnt[NE];
  int tid = threadIdx.x;
  if (tid < NE) lcnt[tid] = 0;
  __syncthreads();
  int base = blockIdx.x * 1024 + tid * 4;
#pragma unroll
  for (int j = 0; j < 4; ++j) atomicAdd(&lcnt[topki[base + j]], 1);
  __syncthreads();
  if (tid < NE) meta[1056 + blockIdx.x * NE + tid] = lcnt[tid];
}

__global__ __launch_bounds__(256) void k_plan(int* __restrict__ meta,
                                              int* __restrict__ ptok,
                                              float* __restrict__ pgate) {
  __shared__ int cnt_s[NE], po_s[NE + 1];
  int tid = threadIdx.x;
  // zero queue counter + g1done + g2done (ws is re-poisoned before every launch)
  for (int i = tid; i < 1120; i += 256) meta[MQ_CTR + i] = 0;
  if (tid < NE) {
    int s = 0;
    for (int b = 0; b < NB_CNT; ++b) s += meta[1056 + b * NE + tid];
    cnt_s[tid] = s;
  }
  __syncthreads();
  if (tid == 0) {
    int off = 0;
    for (int e = 0; e < NE; ++e) {
      po_s[e] = off;
      meta[1 + e] = off;
      off += ((cnt_s[e] + BM - 1) / BM) * BM;
    }
    po_s[NE] = off;
    meta[1 + NE] = off;
    meta[0] = off / BM;
  }
  __syncthreads();
  if (tid < NE) {
    int run = po_s[tid];
    for (int b = 0; b < NB_CNT; ++b) {
      meta[32 + b * NE + tid] = run;
      run += meta[1056 + b * NE + tid];
    }
  }
  for (int e = 0; e < NE; ++e) {
    int start = po_s[e] + cnt_s[e], end = po_s[e + 1];
    for (int i = start + tid; i < end; i += 256) { ptok[i] = 0; pgate[i] = 0.f; }
  }
}

__global__ __launch_bounds__(256) void k_scatter(const int* __restrict__ topki,
                                                 const float* __restrict__ topkg,
                                                 const int* __restrict__ meta,
                                                 int* __restrict__ ptok,
                                                 float* __restrict__ pgate,
                                                 int* __restrict__ sinv) {
  __shared__ int lcnt[NE];
  int tid = threadIdx.x;
  if (tid < NE) lcnt[tid] = 0;
  __syncthreads();
  int base = blockIdx.x * 1024 + tid * 4;
#pragma unroll
  for (int j = 0; j < 4; ++j) {
    int i = base + j;
    int e = topki[i];
    int r = atomicAdd(&lcnt[e], 1);
    int slot = meta[32 + blockIdx.x * NE + e] + r;
    ptok[slot] = i >> 2;
    pgate[slot] = topkg[i];
    sinv[i] = slot;
  }
}

// ---------------- persistent fused MoE GEMM pipeline ----------------
// Work item p: tile=p/20, r=p%20. r<16 -> gemm1 (nblock r); r>=16 -> gemm2 of
// tile-LAG (nblock r-16). h lives in a ring of R tiles.
// Sync: g1done[t] (16 releases) gates gemm2 reads of slot t%R.
//       g2done[t] (4 releases)  gates gemm1 WRITES of slot (t+R)%R — the
//       backpressure that round 4 lacked (queue completes out of order, so the
//       in-flight span is NOT bounded by grid size).
// Deadlock-free: every wait targets strictly-earlier queue positions, so the
// earliest unfinished item is always runnable.
__global__ __launch_bounds__(256, 4) void k_moe(const unsigned short* __restrict__ xb,
                                                const unsigned short* __restrict__ w1t,
                                                const float* __restrict__ b1,
                                                const unsigned short* __restrict__ w2t,
                                                const float* __restrict__ b2,
                                                const int* __restrict__ ptok,
                                                const float* __restrict__ pgate,
                                                int* meta,
                                                unsigned short* hring,
                                                unsigned short* __restrict__ yslot,
                                                int R, int LAG) {
  __shared__ __align__(16) unsigned short Al[BM * BK];
  __shared__ __align__(16) unsigned short Bl[BN * BK];
  __shared__ int s_item;
  int tid = threadIdx.x;
  int lane = tid & 63, w = tid >> 6;
  int wm = w >> 1, wn = w & 1;
  int w4 = w * 4096;
  int sub = lane >> 3;
  int lg = (lane & 7) ^ sub;
  int lrow = lane & 15, quad = lane >> 4;
  int r7 = lrow & 7;
  int tiles = meta[0];
  int seqlen = (tiles + LAG) * 20;
  int* g1done = meta + MQ_G1;
  int* g2done = meta + MQ_G2;

  for (;;) {
    __syncthreads();
    if (tid == 0) s_item = atomicAdd(&meta[MQ_CTR], 1);
    __syncthreads();
    int p = s_item;
    if (p >= seqlen) return;
    int tt = p / 20, r = p % 20;
    if (r < 16) {
      // ======== GEMM1: h[tile%R] = relu(X @ W1[e] + b1[e]) ========
      if (tt >= tiles) continue;
      int tile = tt;
      int row0 = tile * BM;
      int e = 0;
#pragma unroll
      for (int i = 1; i < NE; ++i)
        if (row0 >= meta[1 + i]) e = i;
      int nblock = r * BN;
      const unsigned short* asrc[4];
      const unsigned short* bsrc[4];
#pragma unroll
      for (int t = 0; t < 4; ++t) {
        int rr = w * 32 + t * 8 + sub;
        asrc[t] = xb + (size_t)ptok[row0 + rr] * DIM + lg * 8;
        bsrc[t] = w1t + ((size_t)e * HID + nblock + rr) * DIM + lg * 8;
      }
      f4v acc[4][4] = {};
      for (int k0 = 0; k0 < DIM; k0 += BK) {
#pragma unroll
        for (int t = 0; t < 4; ++t) gload16(asrc[t] + k0, (char*)Al + w4 + t * 1024);
#pragma unroll
        for (int t = 0; t < 4; ++t) gload16(bsrc[t] + k0, (char*)Bl + w4 + t * 1024);
        __syncthreads();
#pragma unroll
        for (int ks = 0; ks < 2; ++ks) {
          int pg = ((ks * 4 + quad) ^ r7) * 8;
          s8v af[4], bfr[4];
#pragma unroll
          for (int mt = 0; mt < 4; ++mt)
            af[mt] = __builtin_bit_cast(s8v, *(const u4v*)&Al[(wm * 64 + mt * 16 + lrow) * BK + pg]);
#pragma unroll
          for (int nt = 0; nt < 4; ++nt)
            bfr[nt] = __builtin_bit_cast(s8v, *(const u4v*)&Bl[(wn * 64 + nt * 16 + lrow) * BK + pg]);
#pragma unroll
          for (int mt = 0; mt < 4; ++mt) {
#pragma unroll
            for (int nt = 0; nt < 4; ++nt)
              acc[mt][nt] = __builtin_amdgcn_mfma_f32_16x16x32_bf16(af[mt], bfr[nt], acc[mt][nt], 0, 0, 0);
          }
        }
        __syncthreads();
      }
      // ---- ring backpressure: previous occupant of this slot must be fully read
      int prev = tile - R;
      if (prev >= 0) {
        if (tid == 0) {
          while (__hip_atomic_load(&g2done[prev], __ATOMIC_ACQUIRE, __HIP_MEMORY_SCOPE_AGENT) < 4)
            __builtin_amdgcn_s_sleep(2);
        }
        __syncthreads();
      }
      unsigned short* hdst = hring + (size_t)(tile % R) * BM * HID;
#pragma unroll
      for (int nt = 0; nt < 4; ++nt) {
        int gcol = nblock + wn * 64 + nt * 16 + lrow;
        float bias = b1[e * HID + gcol];
#pragma unroll
        for (int mt = 0; mt < 4; ++mt) {
#pragma unroll
          for (int j = 0; j < 4; ++j) {
            int grow = wm * 64 + mt * 16 + quad * 4 + j;
            float v = acc[mt][nt][j] + bias;
            hdst[(size_t)grow * HID + gcol] = f2bf(v > 0.f ? v : 0.f);
          }
        }
      }
      __syncthreads();   // all stores drained (vmcnt(0) before barrier)
      if (tid == 0) {
        __threadfence();  // device-visible before flag
        __hip_atomic_fetch_add(&g1done[tile], 1, __ATOMIC_RELEASE, __HIP_MEMORY_SCOPE_AGENT);
      }
    } else {
      // ======== GEMM2: y[slot] = gate*(h[tile%R] @ W2[e] + b2[e]) ========
      int tile = tt - LAG;
      if (tile < 0 || tile >= tiles) continue;
      int row0 = tile * BM;
      int e = 0;
#pragma unroll
      for (int i = 1; i < NE; ++i)
        if (row0 >= meta[1 + i]) e = i;
      int nblock = (r - 16) * BN;
      if (tid == 0) {
        while (__hip_atomic_load(&g1done[tile], __ATOMIC_ACQUIRE, __HIP_MEMORY_SCOPE_AGENT) < 16)
          __builtin_amdgcn_s_sleep(2);
      }
      __syncthreads();
      const unsigned short* hsrc = hring + (size_t)(tile % R) * BM * HID;
      const unsigned short* asrc[4];
      const unsigned short* bsrc[4];
#pragma unroll
      for (int t = 0; t < 4; ++t) {
        int rr = w * 32 + t * 8 + sub;
        asrc[t] = hsrc + (size_t)rr * HID + lg * 8;
        bsrc[t] = w2t + ((size_t)e * DIM + nblock + rr) * HID + lg * 8;
      }
      f4v acc[4][4] = {};
      for (int k0 = 0; k0 < HID; k0 += BK) {
#pragma unroll
        for (int t = 0; t < 4; ++t) gload16(asrc[t] + k0, (char*)Al + w4 + t * 1024);
#pragma unroll
        for (int t = 0; t < 4; ++t) gload16(bsrc[t] + k0, (char*)Bl + w4 + t * 1024);
        __syncthreads();
#pragma unroll
        for (int ks = 0; ks < 2; ++ks) {
          int pg = ((ks * 4 + quad) ^ r7) * 8;
          s8v af[4], bfr[4];
#pragma unroll
          for (int mt = 0; mt < 4; ++mt)
            af[mt] = __builtin_bit_cast(s8v, *(const u4v*)&Al[(wm * 64 + mt * 16 + lrow) * BK + pg]);
#pragma unroll
          for (int nt = 0; nt < 4; ++nt)
            bfr[nt] = __builtin_bit_cast(s8v, *(const u4v*)&Bl[(wn * 64 + nt * 16 + lrow) * BK + pg]);
#pragma unroll
          for (int mt = 0; mt < 4; ++mt) {
#pragma unroll
            for (int nt = 0; nt < 4; ++nt)
              acc[mt][nt] = __builtin_amdgcn_mfma_f32_16x16x32_bf16(af[mt], bfr[nt], acc[mt][nt], 0, 0, 0);
          }
        }
        __syncthreads();
      }
      // all reads of hsrc are complete (vmcnt drained at the loop's barriers):
      // release this tile's ring slot for the next writer.
      if (tid == 0)
        __hip_atomic_fetch_add(&g2done[tile], 1, __ATOMIC_RELEASE, __HIP_MEMORY_SCOPE_AGENT);
      float bias[4];
#pragma unroll
      for (int nt = 0; nt < 4; ++nt)
        bias[nt] = b2[e * DIM + nblock + wn * 64 + nt * 16 + lrow];
#pragma unroll
      for (int mt = 0; mt < 4; ++mt) {
#pragma unroll
        for (int j = 0; j < 4; ++j) {
          int pp = row0 + wm * 64 + mt * 16 + quad * 4 + j;
          float g = pgate[pp];
          unsigned short* yr = yslot + (size_t)pp * DIM + nblock + wn * 64 + lrow;
#pragma unroll
          for (int nt = 0; nt < 4; ++nt)
            yr[nt * 16] = f2bf(g * (acc[mt][nt][j] + bias[nt]));
        }
      }
    }
  }
}

// out[t][d] = sum_k yslot[sinv[t*4+k]][d]   (yslot is bf16)
__global__ __launch_bounds__(256) void k_gather(const unsigned short* __restrict__ yslot,
                                                const int* __restrict__ sinv,
                                                float* __restrict__ out) {
  int id = blockIdx.x * 256 + threadIdx.x;
  int t = id >> 7, d4 = (id & 127) << 2;
  int4 s = *(const int4*)(sinv + t * 4);
  int sl[4] = {s.x, s.y, s.z, s.w};
  float sum0 = 0.f, sum1 = 0.f, sum2 = 0.f, sum3 = 0.f;
#pragma unroll
  for (int k = 0; k < 4; ++k) {
    ushort4 v = *(const ushort4*)(yslot + (size_t)sl[k] * DIM + d4);
    sum0 += bf2f(v.x); sum1 += bf2f(v.y); sum2 += bf2f(v.z); sum3 += bf2f(v.w);
  }
  float4 r; r.x = sum0; r.y = sum1; r.z = sum2; r.w = sum3;
  *(float4*)(out + (size_t)t * DIM + d4) = r;
}

extern "C" void kernel_launch(void* const* d_in, const int* in_sizes, int n_in,
                              void* d_out, int out_size, void* d_ws, size_t ws_size,
                              hipStream_t stream) {
  const float* x  = (const float*)d_in[0];
  const float* rw = (const float*)d_in[1];
  const float* rb = (const float*)d_in[2];
  const float* w1 = (const float*)d_in[3];
  const float* b1 = (const float*)d_in[4];
  const float* w2 = (const float*)d_in[5];
  const float* b2 = (const float*)d_in[6];
  float* out = (float*)d_out;
  char* ws = (char*)d_ws;

  size_t o_xb    = 0;
  size_t o_w1t   = o_xb    + (size_t)T_TOK * DIM * 2;
  size_t o_w2t   = o_w1t   + (size_t)NE * DIM * HID * 2;
  size_t o_topki = o_w2t   + (size_t)NE * DIM * HID * 2;
  size_t o_topkg = o_topki + (size_t)T_TOK * TOPK * 4;
  size_t o_meta  = o_topkg + (size_t)T_TOK * TOPK * 4;
  size_t o_ptok  = o_meta  + 16384;
  size_t o_pgate = o_ptok  + (size_t)PAIR_CAP * 4;
  size_t o_sinv  = o_pgate + (size_t)PAIR_CAP * 4;
  size_t o_yslot = o_sinv  + (size_t)T_TOK * TOPK * 4;
  size_t o_hb    = o_yslot + (size_t)PAIR_CAP * DIM * 2;   // bf16 yslot

  unsigned short* xb   = (unsigned short*)(ws + o_xb);
  unsigned short* w1t  = (unsigned short*)(ws + o_w1t);
  unsigned short* w2t  = (unsigned short*)(ws + o_w2t);
  int*            tki  = (int*)(ws + o_topki);
  float*          tkg  = (float*)(ws + o_topkg);
  int*            meta = (int*)(ws + o_meta);
  int*            ptok = (int*)(ws + o_ptok);
  float*          pgt  = (float*)(ws + o_pgate);
  int*            sinv = (int*)(ws + o_sinv);
  unsigned short* ysl  = (unsigned short*)(ws + o_yslot);
  unsigned short* hring = (unsigned short*)(ws + o_hb);

  size_t tile_h = (size_t)BM * HID * 2;
  size_t avail = ws_size > o_hb ? ws_size - o_hb : 0;
  long Rl = (long)(avail / tile_h);
  int R = (int)(Rl > 544 ? 544 : Rl);          // ring size in tiles (expect ~217)
  int LAG = R / 4 < 32 ? R / 4 : 32;           // gemm2 scheduling lookahead (< R)
  int G = 1024;                                 // 4 blocks/CU x 256 CUs

  k_router<<<T_TOK / 4, 256, 0, stream>>>(x, rw, rb, tki, tkg, xb);
  k_transpose_cast<<<dim3(HID / 32, DIM / 32, NE), dim3(32, 8), 0, stream>>>(w1, w1t, DIM, HID);
  k_transpose_cast<<<dim3(DIM / 32, HID / 32, NE), dim3(32, 8), 0, stream>>>(w2, w2t, HID, DIM);
  k_count<<<NB_CNT, 256, 0, stream>>>(tki, meta);
  k_plan<<<1, 256, 0, stream>>>(meta, ptok, pgt);
  k_scatter<<<NB_CNT, 256, 0, stream>>>(tki, tkg, meta, ptok, pgt, sinv);
  k_moe<<<G, 256, 0, stream>>>(xb, w1t, b1, w2t, b2, ptok, pgt, meta, hring, ysl, R, LAG);
  k_gather<<<T_TOK * DIM / 4 / 256, 256, 0, stream>>>(ysl, sinv, out);
}